// Round 4
// baseline (1003.283 us; speedup 1.0000x reference)
//
#include <hip/hip_runtime.h>
#include <hip/hip_bf16.h>

// Problem constants (reference: FEAT=1024, N_TAR=60000, N_MSG=45000)
#define FEAT 1024
#define NTAR 60000
#define NMSG 45000
#define MPAD 60032    // prep writes this many rows (A1/A2)
#define BM 256
#define BN 256
#define BK 64
#define KT16 (FEAT / BK)        // 16 K-tiles
#define MTILES ((NTAR + BM - 1) / BM)  // 235
#define NTILES (FEAT / BN)      // 4
#define NWG (MTILES * NTILES)   // 940

typedef __bf16 bf16_t;
typedef __attribute__((ext_vector_type(8))) __bf16 bf16x8;
typedef __attribute__((ext_vector_type(4))) __bf16 bf16x4;
typedef __attribute__((ext_vector_type(4))) float f32x4;

#define BAR() asm volatile("s_barrier" ::: "memory")

// ---------------------------------------------------------------------------
__global__ __launch_bounds__(256) void build_inv_kernel(
    const int* __restrict__ o_idx, const int* __restrict__ s_idx,
    int* __restrict__ inv_o, int* __restrict__ inv_s, int n) {
  int i = blockIdx.x * 256 + threadIdx.x;
  if (i < n) {
    inv_o[o_idx[i]] = i;
    inv_s[s_idx[i]] = i;
  }
}

// ---------------------------------------------------------------------------
__global__ __launch_bounds__(256) void convw_kernel(
    const float* __restrict__ w1, const float* __restrict__ w2,
    bf16_t* __restrict__ W1b, bf16_t* __restrict__ W2b) {
  int i = (blockIdx.x * 256 + threadIdx.x) * 4;
  f32x4 v1 = *(const f32x4*)(w1 + i);
  f32x4 v2 = *(const f32x4*)(w2 + i);
  bf16x4 o1, o2;
#pragma unroll
  for (int j = 0; j < 4; ++j) {
    o1[j] = (bf16_t)v1[j];
    o2[j] = (bf16_t)v2[j];
  }
  *(bf16x4*)(W1b + i) = o1;
  *(bf16x4*)(W2b + i) = o2;
}

// ---------------------------------------------------------------------------
__global__ __launch_bounds__(256) void prep_kernel(
    const float* __restrict__ msg_o, const float* __restrict__ msg_s,
    const float* __restrict__ tar,
    const int* __restrict__ inv_o, const int* __restrict__ inv_s,
    bf16_t* __restrict__ A1, bf16_t* __restrict__ A2) {
  const int total = MPAD * (FEAT / 4);
  const int stride = gridDim.x * 256;
#pragma unroll 2
  for (int e = blockIdx.x * 256 + threadIdx.x; e < total; e += stride) {
    const long r = e >> 8;
    const int c = (e & 255) * 4;
    bf16x4 s_out, t_out;
    if (r < NTAR) {
      const int mo = inv_o[r];
      const int ms = inv_s[r];
      f32x4 zed = {0.f, 0.f, 0.f, 0.f};
      f32x4 vo = (mo >= 0) ? *(const f32x4*)(msg_o + (long)mo * FEAT + c) : zed;
      f32x4 vs = (ms >= 0) ? *(const f32x4*)(msg_s + (long)ms * FEAT + c) : zed;
      f32x4 vt = *(const f32x4*)(tar + r * FEAT + c);
#pragma unroll
      for (int j = 0; j < 4; ++j) {
        s_out[j] = (bf16_t)(0.5f * (vo[j] + vs[j]));
        t_out[j] = (bf16_t)vt[j];
      }
    } else {
#pragma unroll
      for (int j = 0; j < 4; ++j) {
        s_out[j] = (bf16_t)0.f;
        t_out[j] = (bf16_t)0.f;
      }
    }
    *(bf16x4*)(A1 + r * FEAT + c) = s_out;
    *(bf16x4*)(A2 + r * FEAT + c) = t_out;
  }
}

// ---------------------------------------------------------------------------
// 256x256 "flow-8" GEMM: one barrier per phase so phase p+1's ds_reads drain
// under phase p's MFMA burst (round-3's 2-BAR lockstep serialized LDS drain
// [~2300cy/kt] + MFMA [~2500cy/kt] -> 9150cy/kt measured; flow target ~3000).
//
// Per kt (buf = kt&1, reads/MFMA on buf; b0 regs pre-read at ph4 of kt-1):
//  ph1: read a_q0[8]    ; stage Bs1(kt+1),Ahi(kt+1)->buf^1 ; BAR ; MFMA(q0,b0)
//  ph2: read b1 [4]     ; stage Bs0(kt+2)->buf             ; BAR ; MFMA(q0,b1)
//  ph3: read a_q1[8]    ; stage Alo(kt+2)->buf             ; BAR ; MFMA(q1,b0)
//  ph4: vmcnt(4) ; BAR ; read b0(kt+1)[4] from buf^1       ;       MFMA(q1,b1)
//
// WAR-safety (stage at p may overwrite R only if R read at q <= p-2):
//  Bs1(kt+1): R read as b1(kt-1) @ph2(kt-1), sep 3 OK. Ahi(kt+1): R read as
//  a_q1(kt-1) @ph3(kt-1), sep 2 OK. Bs0(kt+2): R read @ph4(kt-1) (b0-preread),
//  sep 2 OK. Alo(kt+2): R read @ph1(kt), sep 2 OK.
// vmcnt(4) audit: issue order per kt = [ph1:Bs1,Ahi(kt+1)][ph2:Bs0(kt+2)]
//  [ph3:Alo(kt+2)]; at ph4 outstanding (oldest first) = Bs0(kt+1),Alo(kt+1)
//  [from kt-1], Bs1,Ahi(kt+1), Bs0,Alo(kt+2) = 12 loads; wait-to-4 lands the
//  first 4 stages = ALL of kt+1; leftover = kt+2 pair. Prologue establishes
//  the same invariant (6 stages, vmcnt(4) = kt0 landed, {Bs0,Alo(1)} in
//  flight). Tail: kt>=KT16-2 uses vmcnt(0).
template <bool FUSE_S>
__global__ __launch_bounds__(512, 2) void gemm8_kernel(
    const bf16_t* __restrict__ Ap, const bf16_t* __restrict__ Wp,
    const float* __restrict__ bias, const bf16_t* __restrict__ sS,
    float* __restrict__ out) {
  __shared__ char lds[131072];
  const int tid = threadIdx.x;
  const int lane = tid & 63;
  const int wid = tid >> 6;
  const int wm = wid >> 2;   // 0..1
  const int wn = wid & 3;    // 0..3
  const int g4 = lane >> 4;  // 0..3
  const int r16 = lane & 15;
  const int k7 = r16 & 7;
  const int cb0 = (g4 ^ k7) * 16;        // stored chunk byte, kk=0
  const int cb1 = ((4 + g4) ^ k7) * 16;  // kk=1

  // m204 bijective XCD swizzle, NWG=940: q=117, r=4.
  const int orig = blockIdx.x;
  const int xcd = orig & 7, j = orig >> 3;
  const int wgid = (xcd < 4 ? xcd * 118 : 472 + (xcd - 4) * 117) + j;
  const int mtile = wgid >> 2;
  const int ntile = wgid & 3;
  const long row0 = (long)mtile * BM;
  const int col0 = ntile * BN;

  auto stageA = [&](int buf, int h, int kt) {
#pragma unroll
    for (int i = 0; i < 2; ++i) {
      const int idx = i * 512 + tid;
      const int rl = idx >> 3;
      const int row = (rl & 63) + ((rl >> 6) << 7) + (h << 6);
      const int gc = (idx & 7) ^ (rl & 7);
      const bf16_t* src = Ap + (row0 + row) * FEAT + kt * BK + gc * 8;
      __builtin_amdgcn_global_load_lds(
          (const __attribute__((address_space(1))) void*)src,
          (__attribute__((address_space(3))) void*)(lds + buf * 65536 +
                                                    h * 16384 + idx * 16),
          16, 0, 0);
    }
  };
  auto stageB = [&](int buf, int s, int kt) {
#pragma unroll
    for (int i = 0; i < 2; ++i) {
      const int idx = i * 512 + tid;
      const int rl = idx >> 3;
      const int row = (rl & 31) + ((rl >> 5) << 6) + (s << 5);
      const int gc = (idx & 7) ^ (rl & 7);
      const bf16_t* src = Wp + (long)(col0 + row) * FEAT + kt * BK + gc * 8;
      __builtin_amdgcn_global_load_lds(
          (const __attribute__((address_space(1))) void*)src,
          (__attribute__((address_space(3))) void*)(lds + buf * 65536 + 32768 +
                                                    s * 16384 + idx * 16),
          16, 0, 0);
    }
  };

  f32x4 acc[8][4] = {};
  bf16x8 a[4][2], b0[2][2], b1[2][2];

  auto loadA = [&](const char* L, int q) {
#pragma unroll
    for (int m2 = 0; m2 < 4; ++m2) {
      const char* p = L + q * 16384 + (wm * 64 + m2 * 16 + r16) * 128;
      a[m2][0] = *(const bf16x8*)(p + cb0);
      a[m2][1] = *(const bf16x8*)(p + cb1);
    }
  };
  auto loadB = [&](const char* L, int s, bf16x8(&b)[2][2]) {
#pragma unroll
    for (int nn = 0; nn < 2; ++nn) {
      const char* p = L + 32768 + s * 16384 + (wn * 32 + nn * 16 + r16) * 128;
      b[nn][0] = *(const bf16x8*)(p + cb0);
      b[nn][1] = *(const bf16x8*)(p + cb1);
    }
  };
  auto mfma16 = [&](int q, int s, bf16x8(&b)[2][2]) {
    __builtin_amdgcn_s_setprio(1);
#pragma unroll
    for (int m2 = 0; m2 < 4; ++m2)
#pragma unroll
      for (int nn = 0; nn < 2; ++nn)
#pragma unroll
        for (int kk = 0; kk < 2; ++kk)
          acc[q * 4 + m2][s * 2 + nn] = __builtin_amdgcn_mfma_f32_16x16x32_bf16(
              a[m2][kk], b[nn][kk], acc[q * 4 + m2][s * 2 + nn], 0, 0, 0);
    __builtin_amdgcn_s_setprio(0);
  };

  // Prologue: kt0 {Alo,Bs0,Bs1,Ahi} + {Bs0(1),Alo(1)} -- order matters for vmcnt.
  stageA(0, 0, 0); stageB(0, 0, 0); stageB(0, 1, 0); stageA(0, 1, 0);
  stageB(1, 0, 1); stageA(1, 0, 1);
  asm volatile("s_waitcnt vmcnt(4)" ::: "memory");  // kt0 landed; kt1 pair in flight
  BAR();
  loadB(lds, 0, b0);  // b0(kt=0) pre-read (steady-state contract)

  for (int kt = 0; kt < KT16; ++kt) {
    const int buf = kt & 1;
    const char* L = lds + buf * 65536;
    const char* Ln = lds + (buf ^ 1) * 65536;
    // ---- ph1
    loadA(L, 0);
    if (kt + 1 < KT16) { stageB(buf ^ 1, 1, kt + 1); stageA(buf ^ 1, 1, kt + 1); }
    BAR();
    mfma16(0, 0, b0);
    // ---- ph2
    loadB(L, 1, b1);
    if (kt + 2 < KT16) stageB(buf, 0, kt + 2);
    BAR();
    mfma16(0, 1, b1);
    // ---- ph3
    loadA(L, 1);
    if (kt + 2 < KT16) stageA(buf, 0, kt + 2);
    BAR();
    mfma16(1, 0, b0);
    // ---- ph4
    if (kt < KT16 - 2)
      asm volatile("s_waitcnt vmcnt(4)" ::: "memory");  // kt+1 fully landed
    else
      asm volatile("s_waitcnt vmcnt(0)" ::: "memory");
    BAR();
    if (kt + 1 < KT16) loadB(Ln, 0, b0);  // pre-read b0(kt+1); drains under MFMA
    mfma16(1, 1, b1);
  }

  // Epilogue. C/D frag layout: col=lane&15, row=(lane>>4)*4+reg (m89/m91).
  float bv[4];
#pragma unroll
  for (int ni = 0; ni < 4; ++ni) bv[ni] = bias[col0 + wn * 64 + ni * 16 + r16];
#pragma unroll
  for (int mi = 0; mi < 8; ++mi) {
    const int q = mi >> 2, m2 = mi & 3;
#pragma unroll
    for (int r = 0; r < 4; ++r) {
      const long row = row0 + wm * 128 + q * 64 + m2 * 16 + g4 * 4 + r;
      if (row < NTAR) {
#pragma unroll
        for (int ni = 0; ni < 4; ++ni) {
          const int col = col0 + wn * 64 + ni * 16 + r16;
          float v = fmaxf(acc[mi][ni][r] + bv[ni], 0.f);
          if (FUSE_S) {
            v += (float)sS[row * FEAT + col];
            out[row * FEAT + col] = v;
          } else {
            out[row * FEAT + col] += v;
          }
        }
      }
    }
  }
}

// ---------------------------------------------------------------------------
extern "C" void kernel_launch(void* const* d_in, const int* in_sizes, int n_in,
                              void* d_out, int out_size, void* d_ws, size_t ws_size,
                              hipStream_t stream) {
  const float* msg_o = (const float*)d_in[0];
  const float* msg_s = (const float*)d_in[1];
  const int* o_idx = (const int*)d_in[2];
  const int* s_idx = (const int*)d_in[3];
  const float* tar = (const float*)d_in[4];
  const float* w1 = (const float*)d_in[5];
  const float* b1 = (const float*)d_in[6];
  const float* w2 = (const float*)d_in[7];
  const float* b2 = (const float*)d_in[8];
  float* out = (float*)d_out;

  char* ws = (char*)d_ws;
  bf16_t* A1 = (bf16_t*)ws;
  bf16_t* A2 = (bf16_t*)(ws + (size_t)MPAD * FEAT * 2);
  bf16_t* W1b = (bf16_t*)(ws + (size_t)MPAD * FEAT * 4);
  bf16_t* W2b = (bf16_t*)(ws + (size_t)MPAD * FEAT * 4 + (size_t)FEAT * FEAT * 2);
  int* inv_o = (int*)(ws + (size_t)MPAD * FEAT * 4 + (size_t)FEAT * FEAT * 4);
  int* inv_s = inv_o + MPAD;

  hipMemsetAsync(inv_o, 0xFF, (size_t)MPAD * 2 * sizeof(int), stream);
  build_inv_kernel<<<(NMSG + 255) / 256, 256, 0, stream>>>(o_idx, s_idx, inv_o,
                                                           inv_s, NMSG);
  convw_kernel<<<(FEAT * FEAT / 4) / 256, 256, 0, stream>>>(w1, w2, W1b, W2b);
  prep_kernel<<<4096, 256, 0, stream>>>(msg_o, msg_s, tar, inv_o, inv_s, A1, A2);
  gemm8_kernel<true><<<NWG, 512, 0, stream>>>(A1, W1b, b1, A1, out);
  gemm8_kernel<false><<<NWG, 512, 0, stream>>>(A2, W2b, b2, (const bf16_t*)nullptr, out);
}